// Round 15
// baseline (459.090 us; speedup 1.0000x reference)
//
#include <hip/hip_runtime.h>
#include <hip/hip_bf16.h>
#include <math.h>

#define KDIM 5
#define KC 125
#define KPAD 8192   // permuted K space (levels 2/3): 128 wi-rows x 64 ch
#define EPB 32      // max_nb = 32 -> deg <= 32 always
#define NSPLIT 4    // GEMM K-split for levels 2/3
#define LDA 72      // GEMM LDS tile row stride in bf16 (64 + 8 pad)
#define SSTR 40     // buildA S row stride in bf16 (80B rows, 16B-aligned frags)
#define XSTR 48     // buildA XT row stride in bf16 (96B rows; stride 48 mod 32 = 16 banks -> 2-way free)
#define H1STR 40    // histo1 S row stride in bf16

typedef short bf16x8 __attribute__((ext_vector_type(8)));
typedef float f32x4 __attribute__((ext_vector_type(4)));

__device__ __forceinline__ float elu_f(float x) { return x > 0.f ? x : (expf(x) - 1.f); }

__device__ __forceinline__ void fadd_atomic(float* p, float v) {
    unsafeAtomicAdd(p, v);
}

__device__ __forceinline__ unsigned short f2bf(float x) {
    union { float f; unsigned u; } v; v.f = x;
    unsigned r = (v.u + 0x7FFFu + ((v.u >> 16) & 1u)) >> 16;
    return (unsigned short)r;
}
__device__ __forceinline__ unsigned pack2(float lo, float hi) {
    __hip_bfloat162 h = __float22bfloat162_rn(make_float2(lo, hi));
    unsigned r; __builtin_memcpy(&r, &h, 4); return r;
}

// ---------------- rowptr ----------------
__global__ void rowptr_kernel(const int* __restrict__ tgt, int E, int n, int* __restrict__ rowptr)
{
    int e = blockIdx.x * blockDim.x + threadIdx.x;
    if (e > E) return;
    if (e < E) {
        int t = tgt[e];
        int p = (e == 0) ? -1 : tgt[e - 1];
        for (int v = p + 1; v <= t; v++) rowptr[v] = e;
    } else {
        int p = tgt[E - 1];
        for (int v = p + 1; v <= n; v++) rowptr[v] = E;
    }
}

// ---------------- slot table ----------------
__global__ void slots_kernel(const float* __restrict__ posL, const int* __restrict__ src,
                             const int* __restrict__ tgt, int E, float rinv2, int sinkrow,
                             unsigned* __restrict__ slots)
{
    int e = blockIdx.x * blockDim.x + threadIdx.x;
    if (e >= E) return;
    int s = src[e], t = tgt[e];
    float p0 = fminf(fmaxf((posL[t*3+0] - posL[s*3+0]) * rinv2 + 0.5f, 0.f), 1.f);
    float p1 = fminf(fmaxf((posL[t*3+1] - posL[s*3+1]) * rinv2 + 0.5f, 0.f), 1.f);
    float p2 = fminf(fmaxf((posL[t*3+2] - posL[s*3+2]) * rinv2 + 0.5f, 0.f), 1.f);
    float v0 = p0 * (KDIM - 1), v1 = p1 * (KDIM - 1), v2 = p2 * (KDIM - 1);
    int b0 = (int)floorf(v0), b1 = (int)floorf(v1), b2 = (int)floorf(v2);
    float f0 = v0 - (float)b0, f1 = v1 - (float)b1, f2 = v2 - (float)b2;
    unsigned out[8];
    #pragma unroll
    for (int sb = 0; sb < 8; sb++) {
        int i0 = sb & 1, i1 = (sb >> 1) & 1, i2 = (sb >> 2) & 1;
        float w = (i0 ? f0 : 1.f - f0) * (i1 ? f1 : 1.f - f1) * (i2 ? f2 : 1.f - f2);
        int k0 = min(b0 + i0, KDIM - 1), k1 = min(b1 + i1, KDIM - 1), k2 = min(b2 + i2, KDIM - 1);
        int wi = k0 + KDIM * k1 + KDIM * KDIM * k2;
        if (w == 0.f) wi = sinkrow;
        out[sb] = (__float_as_uint(w) & ~127u) | (unsigned)wi;
    }
    uint4* dst = (uint4*)&slots[(size_t)e * 8];
    dst[0] = make_uint4(out[0], out[1], out[2], out[3]);
    dst[1] = make_uint4(out[4], out[5], out[6], out[7]);
}

// ---------------- Level 1 histogram via MFMA row-sum (atomic-free) ----------------
__global__ __launch_bounds__(256) void histo1_kernel(const unsigned* __restrict__ slots,
                                                     const int* __restrict__ rowptr,
                                                     unsigned short* __restrict__ Aout)
{
    __shared__ __attribute__((aligned(16))) unsigned short S[4][128 * H1STR];
    int wave = threadIdx.x >> 6, lane = threadIdx.x & 63;
    int node = blockIdx.x * 4 + wave;
    int rs = rowptr[node], re = rowptr[node + 1];
    int deg = re - rs;
    unsigned short* Sw = S[wave];

    for (int i = lane; i < 128 * H1STR / 8; i += 64)
        ((uint4*)Sw)[i] = make_uint4(0, 0, 0, 0);

    int wbase = lane * 4;
    if (wbase < deg * 8) {
        uint4 sw = *(const uint4*)&slots[(size_t)rs * 8 + wbase];
        unsigned wd[4] = {sw.x, sw.y, sw.z, sw.w};
        #pragma unroll
        for (int j = 0; j < 4; j++) {
            int e = (wbase + j) >> 3;
            int wi = wd[j] & 127u;
            Sw[wi * H1STR + e] = f2bf(__uint_as_float(wd[j] & ~127u));
        }
    }
    __syncthreads();

    const short one = 0x3F80;
    bf16x8 bones = {one, one, one, one, one, one, one, one};
    int fr = lane & 15, fq = (lane >> 4) * 8;
    f32x4 acc[8];
    #pragma unroll
    for (int tl = 0; tl < 8; tl++) {
        bf16x8 af = *(const bf16x8*)&Sw[(tl * 16 + fr) * H1STR + fq];
        acc[tl] = __builtin_amdgcn_mfma_f32_16x16x32_bf16(
            af, bones, (f32x4){0.f, 0.f, 0.f, 0.f}, 0, 0, 0);
    }

    float invdeg = 1.f / fmaxf((float)deg, 1.f);
    if ((lane & 15) == 0) {
        int rbase = (lane >> 4) * 4;
        #pragma unroll
        for (int tl = 0; tl < 8; tl++)
            #pragma unroll
            for (int r = 0; r < 4; r++) {
                int row = tl * 16 + rbase + r;
                float v = (row < KC) ? acc[tl][r] * invdeg : (row == KC ? 1.f : 0.f);
                Sw[row] = f2bf(v);
            }
    }
    unsigned lo = Sw[2 * lane], hi = Sw[2 * lane + 1];
    ((unsigned*)(Aout + (size_t)node * 128))[lane] = lo | (hi << 16);
}

// ---------------- buildA (levels 2/3): MFMA, permuted coalesced writeout ----------------
// A row (node) stores 8192 bf16 in MFMA C-layout order f = tid*32 + i*16 + j*4 + r.
// Root x values injected into wi=126 slots (wave 3, quad 3, r=2); WfT permuted to match.
__global__ __launch_bounds__(256) void buildA_kernel(
    const unsigned* __restrict__ slots, const int* __restrict__ src,
    const int* __restrict__ rowptr, const unsigned short* __restrict__ xbf,
    int nodeBase, unsigned short* __restrict__ Aout)
{
    __shared__ __attribute__((aligned(16))) unsigned short S[128 * SSTR];   // S[wi][e]
    __shared__ __attribute__((aligned(16))) unsigned short XT[64 * XSTR];   // XT[c][e]
    __shared__ int Es[EPB];
    int node = nodeBase + blockIdx.x;
    int t = threadIdx.x;                      // blockDim = 256
    int rs = rowptr[node], re = rowptr[node + 1];
    int ne = re - rs;                         // <= 32 (max_nb)
    int wave = t >> 6, lane = t & 63;
    int fr = lane & 15, fq = (lane >> 4) * 8;

    for (int i = t; i < 128 * SSTR / 2; i += 256) ((unsigned*)S)[i] = 0;
    for (int i = t; i < 64 * XSTR / 2; i += 256) ((unsigned*)XT)[i] = 0;
    if (t < ne) Es[t] = src[rs + t];
    __syncthreads();
    if (t < ne * 8) {
        int e = t >> 3;
        unsigned word = slots[(size_t)rs * 8 + t];
        int wi = word & 127u;
        S[wi * SSTR + e] = f2bf(__uint_as_float(word & ~127u));
    }
    for (int i = t; i < ne * 64; i += 256) {
        int c = i & 63, el = i >> 6;
        XT[c * XSTR + el] = xbf[(size_t)Es[el] * 64 + c];
    }
    __syncthreads();

    f32x4 acc[2][4];
    #pragma unroll
    for (int i = 0; i < 2; i++)
        #pragma unroll
        for (int j = 0; j < 4; j++) acc[i][j] = (f32x4){0.f, 0.f, 0.f, 0.f};
    #pragma unroll
    for (int i = 0; i < 2; i++) {
        bf16x8 af = *(const bf16x8*)&S[((2 * wave + i) * 16 + fr) * SSTR + fq];
        #pragma unroll
        for (int j = 0; j < 4; j++) {
            bf16x8 bg = *(const bf16x8*)&XT[(j * 16 + fr) * XSTR + fq];
            acc[i][j] = __builtin_amdgcn_mfma_f32_16x16x32_bf16(af, bg, acc[i][j], 0, 0, 0);
        }
    }

    float invdeg = 1.f / fmaxf((float)ne, 1.f);
    unsigned pka[16];
    #pragma unroll
    for (int i = 0; i < 2; i++)
        #pragma unroll
        for (int j = 0; j < 4; j++) {
            pka[i * 8 + j * 2 + 0] = pack2(acc[i][j][0] * invdeg, acc[i][j][1] * invdeg);
            pka[i * 8 + j * 2 + 1] = pack2(acc[i][j][2] * invdeg, acc[i][j][3] * invdeg);
        }
    if (wave == 3 && (lane >> 4) == 3) {      // wi = 126 slots carry root x[node]
        #pragma unroll
        for (int j = 0; j < 4; j++) {
            int c = j * 16 + fr;
            unsigned xv = xbf[(size_t)node * 64 + c];
            int idx = 9 + j * 2;              // pair (r=2, r=3); r=2 is low half
            pka[idx] = (pka[idx] & 0xFFFF0000u) | xv;
        }
    }
    unsigned short* out = Aout + (size_t)blockIdx.x * KPAD + t * 32;
    #pragma unroll
    for (int q = 0; q < 4; q++)
        *(uint4*)&out[q * 8] = ((const uint4*)pka)[q];
}

// ---------------- concatWT (level 1, kpad=128, non-permuted) ----------------
__global__ void concatWT_kernel(const float* __restrict__ W, const float* __restrict__ R,
                                int COUT, int kpad, int krows, int cin,
                                unsigned short* __restrict__ WfT)
{
    int i = blockIdx.x * blockDim.x + threadIdx.x;
    if (i >= COUT * kpad) return;
    int n = i / kpad, k = i - n * kpad;
    float v = 0.f;
    if (k < krows) v = W[(size_t)k * COUT + n];
    else if (k < krows + cin) v = R[(size_t)(k - krows) * COUT + n];
    WfT[i] = f2bf(v);
}

// ---------------- concatWTperm (levels 2/3): matches buildA's C-layout K permutation ----
__global__ void concatWTperm_kernel(const float* __restrict__ W, const float* __restrict__ R,
                                    int COUT, unsigned short* __restrict__ WfT)
{
    int idx = blockIdx.x * blockDim.x + threadIdx.x;
    if (idx >= COUT * KPAD) return;
    int n = idx >> 13, f = idx & (KPAD - 1);
    int t = f >> 5, rem = f & 31;
    int i = rem >> 4, j = (rem >> 2) & 3, r = rem & 3;
    int wave = t >> 6, lane = t & 63;
    int wi = (2 * wave + i) * 16 + (lane >> 4) * 4 + r;
    int c = j * 16 + (lane & 15);
    float v = 0.f;
    if (wi < KC) v = W[(size_t)(wi * 64 + c) * COUT + n];
    else if (wi == 126) v = R[(size_t)c * COUT + n];
    WfT[idx] = f2bf(v);
}

// ---------------- bf16 MFMA GEMM, double-buffered LDS ----------------
__global__ __launch_bounds__(256) void gemm_kernel(const unsigned short* __restrict__ A,
                                                   const unsigned short* __restrict__ BT,
                                                   int Mrows, int COUT, int Ksz, int lda,
                                                   float* __restrict__ P)
{
    __shared__ __attribute__((aligned(16))) unsigned short As[2 * 64 * LDA];
    __shared__ __attribute__((aligned(16))) unsigned short Bs[2 * 64 * LDA];
    int t = threadIdx.x;
    int mblk = blockIdx.x * 64, nblk = blockIdx.y * 64;
    int kBase = blockIdx.z * Ksz;

    int lr = t >> 2;
    int lc = (t & 3) * 16;

    const unsigned short* Ap = A + (size_t)(mblk + lr) * lda + kBase + lc;
    const unsigned short* Bp = BT + (size_t)(nblk + lr) * lda + kBase + lc;

    uint4 a0 = *(const uint4*)Ap;  uint4 a1 = *(const uint4*)(Ap + 8);
    uint4 b0 = *(const uint4*)Bp;  uint4 b1 = *(const uint4*)(Bp + 8);

    int wave = t >> 6, lane = t & 63;
    int mw = (wave & 1) * 32, nw = (wave >> 1) * 32;
    int fr = lane & 15;
    int fq = (lane >> 4) * 8;

    f32x4 acc[2][2];
    #pragma unroll
    for (int i = 0; i < 2; i++)
        #pragma unroll
        for (int j = 0; j < 2; j++) acc[i][j] = (f32x4){0.f, 0.f, 0.f, 0.f};

    *(uint4*)&As[lr * LDA + lc]     = a0;
    *(uint4*)&As[lr * LDA + lc + 8] = a1;
    *(uint4*)&Bs[lr * LDA + lc]     = b0;
    *(uint4*)&Bs[lr * LDA + lc + 8] = b1;
    __syncthreads();

    int ktiles = Ksz / 64;
    for (int kt = 0; kt < ktiles; kt++) {
        int cur = (kt & 1) * 64 * LDA;
        if (kt + 1 < ktiles) {
            Ap += 64; Bp += 64;
            a0 = *(const uint4*)Ap; a1 = *(const uint4*)(Ap + 8);
            b0 = *(const uint4*)Bp; b1 = *(const uint4*)(Bp + 8);
        }
        #pragma unroll
        for (int ks = 0; ks < 2; ks++) {
            bf16x8 af0 = *(const bf16x8*)&As[cur + (mw + fr) * LDA + ks * 32 + fq];
            bf16x8 af1 = *(const bf16x8*)&As[cur + (mw + 16 + fr) * LDA + ks * 32 + fq];
            bf16x8 bg0 = *(const bf16x8*)&Bs[cur + (nw + fr) * LDA + ks * 32 + fq];
            bf16x8 bg1 = *(const bf16x8*)&Bs[cur + (nw + 16 + fr) * LDA + ks * 32 + fq];
            acc[0][0] = __builtin_amdgcn_mfma_f32_16x16x32_bf16(af0, bg0, acc[0][0], 0, 0, 0);
            acc[0][1] = __builtin_amdgcn_mfma_f32_16x16x32_bf16(af0, bg1, acc[0][1], 0, 0, 0);
            acc[1][0] = __builtin_amdgcn_mfma_f32_16x16x32_bf16(af1, bg0, acc[1][0], 0, 0, 0);
            acc[1][1] = __builtin_amdgcn_mfma_f32_16x16x32_bf16(af1, bg1, acc[1][1], 0, 0, 0);
        }
        if (kt + 1 < ktiles) {
            int nxt = ((kt + 1) & 1) * 64 * LDA;
            *(uint4*)&As[nxt + lr * LDA + lc]     = a0;
            *(uint4*)&As[nxt + lr * LDA + lc + 8] = a1;
            *(uint4*)&Bs[nxt + lr * LDA + lc]     = b0;
            *(uint4*)&Bs[nxt + lr * LDA + lc + 8] = b1;
        }
        __syncthreads();
    }
    float* Pz = P + (size_t)blockIdx.z * Mrows * COUT;
    int crow = (lane >> 4) * 4, ccol = lane & 15;
    #pragma unroll
    for (int i = 0; i < 2; i++)
        #pragma unroll
        for (int j = 0; j < 2; j++) {
            int m0 = mblk + mw + i * 16 + crow;
            int n0 = nblk + nw + j * 16 + ccol;
            #pragma unroll
            for (int r = 0; r < 4; r++)
                Pz[(size_t)(m0 + r) * COUT + n0] = acc[i][j][r];
        }
}

// ---------------- combine K-split partials + bias + ELU ----------------
__global__ void combine_kernel(const float* __restrict__ P, const float* __restrict__ b,
                               int Mrows, int COUT, int NS, float* __restrict__ xout)
{
    int i = blockIdx.x * blockDim.x + threadIdx.x;
    int total = Mrows * COUT;
    if (i >= total) return;
    float s = 0.f;
    for (int z = 0; z < NS; z++) s += P[(size_t)z * total + i];
    int o = i % COUT;
    xout[i] = elu_f(s + b[o]);
}

// ---------------- gathers ----------------
__global__ void xgather_kernel(const float* __restrict__ x_src, const int* __restrict__ idx,
                               int n, unsigned short* __restrict__ x_dst)
{
    int tid = blockIdx.x * blockDim.x + threadIdx.x;
    if (tid >= n * 64) return;
    int i = tid >> 6, c = tid & 63;
    x_dst[tid] = f2bf(x_src[(size_t)idx[i] * 64 + c]);
}

__global__ void posgather_kernel(const float* __restrict__ pos_src, const int* __restrict__ idx,
                                 int n, float* __restrict__ pos_dst)
{
    int tid = blockIdx.x * blockDim.x + threadIdx.x;
    if (tid >= n * 3) return;
    int i = tid / 3, d = tid - i * 3;
    pos_dst[tid] = pos_src[idx[i] * 3 + d];
}

__global__ void zero_kernel(float* __restrict__ p, int n)
{
    int i = blockIdx.x * blockDim.x + threadIdx.x;
    if (i < n) p[i] = 0.f;
}

// ---------------- cloud ids + counts ----------------
__global__ void cid_kernel(const int* __restrict__ batch, const int* __restrict__ idx1,
                           const int* __restrict__ idx2, int n3,
                           int* __restrict__ cid, float* __restrict__ cnt)
{
    __shared__ int h[16];
    int t = threadIdx.x;
    int i = blockIdx.x * 256 + t;
    if (t < 16) h[t] = 0;
    __syncthreads();
    if (i < n3) {
        int cl = batch[idx1[idx2[i]]];
        cid[i] = cl;
        atomicAdd(&h[cl], 1);
    }
    __syncthreads();
    if (t < 16 && h[t] > 0) fadd_atomic(&cnt[t], (float)h[t]);
}

// ---------------- Mean-pool stage ----------------
__global__ void pool2_kernel(const float* __restrict__ x3, const int* __restrict__ cid,
                             int n3, float* __restrict__ gnum)
{
    int t = threadIdx.x;
    int c = t & 127, h = t >> 7;
    int base = blockIdx.x * 64;
    int nn = min(64, n3 - base);
    float sum = 0.f; int cur = -1;
    for (int j = h; j < nn; j += 2) {
        int i = base + j;
        int cl = cid[i];
        if (cl != cur) {
            if (cur >= 0) fadd_atomic(&gnum[cur * 128 + c], sum);
            cur = cl; sum = 0.f;
        }
        sum += x3[(size_t)i * 128 + c];
    }
    if (cur >= 0) fadd_atomic(&gnum[cur * 128 + c], sum);
}

// ---------------- Final MLP + log_softmax ----------------
__global__ void mlp_kernel(const float* __restrict__ gnum, const float* __restrict__ cnt,
                           const float* __restrict__ lw1, const float* __restrict__ lb1,
                           const float* __restrict__ lw2, const float* __restrict__ lb2,
                           const float* __restrict__ lw3, const float* __restrict__ lb3,
                           float* __restrict__ out)
{
    __shared__ float gv[128], h1[256], h2[256], lg[10];
    __shared__ float lse_s;
    int cl = blockIdx.x, t = threadIdx.x;   // blockDim = 256
    if (t < 128) gv[t] = gnum[cl * 128 + t] / fmaxf(cnt[cl], 1.f);
    __syncthreads();
    float a = lb1[t];
    for (int c = 0; c < 128; c++) a += gv[c] * lw1[c * 256 + t];
    h1[t] = elu_f(a);
    __syncthreads();
    a = lb2[t];
    for (int c = 0; c < 256; c++) a += h1[c] * lw2[c * 256 + t];
    h2[t] = elu_f(a);
    __syncthreads();
    if (t < 10) {
        a = lb3[t];
        for (int c = 0; c < 256; c++) a += h2[c] * lw3[c * 10 + t];
        lg[t] = a;
    }
    __syncthreads();
    if (t == 0) {
        float m = -1e30f;
        for (int i = 0; i < 10; i++) m = fmaxf(m, lg[i]);
        float s = 0.f;
        for (int i = 0; i < 10; i++) s += expf(lg[i] - m);
        lse_s = m + logf(s);
    }
    __syncthreads();
    if (t < 10) out[cl * 10 + t] = lg[t] - lse_s;
}

static void run_level(const unsigned* slots, const int* src, const int* rowptr,
                      const unsigned short* xbf, const unsigned short* WfT, const float* bvec,
                      int n, int COUT, unsigned short* Abuf, int AbufRows, float* P,
                      float* xout, hipStream_t stream)
{
    int Ksz = KPAD / NSPLIT;
    for (int cs = 0; cs < n; cs += AbufRows) {
        int cr = min(AbufRows, n - cs);
        buildA_kernel<<<cr, 256, 0, stream>>>(slots, src, rowptr, xbf, cs, Abuf);
        dim3 grid(cr / 64, COUT / 64, NSPLIT);
        gemm_kernel<<<grid, 256, 0, stream>>>(Abuf, WfT, cr, COUT, Ksz, KPAD, P);
        combine_kernel<<<(cr * COUT + 255) / 256, 256, 0, stream>>>(P, bvec, cr, COUT, NSPLIT,
                                                                    xout + (size_t)cs * COUT);
    }
}

extern "C" void kernel_launch(void* const* d_in, const int* in_sizes, int n_in,
                              void* d_out, int out_size, void* d_ws, size_t ws_size,
                              hipStream_t stream)
{
    const float* pos   = (const float*)d_in[0];
    const int*   batch = (const int*)d_in[1];
    const int*   src1  = (const int*)d_in[2];
    const int*   tgt1  = (const int*)d_in[3];
    const int*   src2  = (const int*)d_in[4];
    const int*   tgt2  = (const int*)d_in[5];
    const int*   src3  = (const int*)d_in[6];
    const int*   tgt3  = (const int*)d_in[7];
    const int*   idx1  = (const int*)d_in[8];
    const int*   idx2  = (const int*)d_in[9];
    const float* W1 = (const float*)d_in[10];
    const float* R1 = (const float*)d_in[11];
    const float* b1 = (const float*)d_in[12];
    const float* W2 = (const float*)d_in[13];
    const float* R2 = (const float*)d_in[14];
    const float* b2 = (const float*)d_in[15];
    const float* W3 = (const float*)d_in[16];
    const float* R3 = (const float*)d_in[17];
    const float* b3 = (const float*)d_in[18];
    const float* lw1 = (const float*)d_in[19];
    const float* lb1 = (const float*)d_in[20];
    const float* lw2 = (const float*)d_in[21];
    const float* lb2 = (const float*)d_in[22];
    const float* lw3 = (const float*)d_in[23];
    const float* lb3 = (const float*)d_in[24];

    int n1 = in_sizes[0] / 3;
    int E1 = in_sizes[2];
    int E2 = in_sizes[4];
    int E3 = in_sizes[6];
    int n2 = in_sizes[8];
    int n3 = in_sizes[9];

    float* ws = (float*)d_ws;
    float* x1   = ws;                               // n1*64 f32
    float* x2o  = x1   + (size_t)n1 * 64;           // n2*64 f32
    float* x3o  = x2o  + (size_t)n2 * 64;           // n3*128 f32
    float* pos2 = x3o  + (size_t)n3 * 128;          // n2*3
    float* pos3 = pos2 + (size_t)n2 * 3;            // n3*3
    float* gnum = pos3 + (size_t)n3 * 3;            // 16*128
    float* cnt  = gnum + 16 * 128;                  // 16
    int*   cid  = (int*)(cnt + 16);                 // n3
    unsigned short* x2in = (unsigned short*)(cid + ((n3 + 4) & ~3));   // n2*64 bf16
    unsigned short* x3in = x2in + (size_t)n2 * 64;                     // n3*64 bf16
    unsigned short* WfT1 = x3in + (size_t)n3 * 64;                     // 64*128 bf16
    unsigned short* WfT2 = WfT1 + (size_t)64 * 128;        // 64*KPAD
    unsigned short* WfT3 = WfT2 + (size_t)64 * KPAD;       // 128*KPAD
    int*   rp1  = (int*)(WfT3 + (size_t)128 * KPAD);
    int*   rp2  = rp1 + ((n1 + 4) & ~3);
    int*   rp3  = rp2 + ((n2 + 4) & ~3);
    unsigned* slots1 = (unsigned*)(rp3 + ((n3 + 4) & ~3));
    unsigned* slots2 = slots1 + (size_t)E1 * 8;
    unsigned* slots3 = slots2 + (size_t)E2 * 8;
    unsigned short* A1buf = (unsigned short*)(slots3 + (size_t)E3 * 8);  // n1*128 bf16
    float*  P    = (float*)(A1buf + (size_t)n1 * 128);  // 8M floats
    unsigned short* Abuf = (unsigned short*)(P + (size_t)8 * 1024 * 1024);

    size_t usedBytes = (size_t)((char*)Abuf - (char*)ws);
    size_t availBytes = ws_size > usedBytes ? ws_size - usedBytes : 0;
    int maxRows = (int)(availBytes / ((size_t)KPAD * 2));
    maxRows &= ~63;
    if (maxRows < 64) maxRows = 64;
    int rowsP2 = ((8 * 1024 * 1024) / (NSPLIT * 64)) & ~63;
    int rowsP3 = ((8 * 1024 * 1024) / (NSPLIT * 128)) & ~63;
    int rows2 = min(min(maxRows, rowsP2), n2);
    int rows3 = min(min(maxRows, rowsP3), n3);

    float* out = (float*)d_out;

    // --- graph preprocessing ---
    rowptr_kernel<<<(E1 + 256) / 256, 256, 0, stream>>>(tgt1, E1, n1, rp1);
    rowptr_kernel<<<(E2 + 256) / 256, 256, 0, stream>>>(tgt2, E2, n2, rp2);
    rowptr_kernel<<<(E3 + 256) / 256, 256, 0, stream>>>(tgt3, E3, n3, rp3);
    posgather_kernel<<<(n2 * 3 + 255) / 256, 256, 0, stream>>>(pos, idx1, n2, pos2);
    posgather_kernel<<<(n3 * 3 + 255) / 256, 256, 0, stream>>>(pos2, idx2, n3, pos3);
    slots_kernel<<<(E1 + 255) / 256, 256, 0, stream>>>(pos,  src1, tgt1, E1, 2.5f,  126, slots1);
    slots_kernel<<<(E2 + 255) / 256, 256, 0, stream>>>(pos2, src2, tgt2, E2, 1.25f, 125, slots2);
    slots_kernel<<<(E3 + 255) / 256, 256, 0, stream>>>(pos3, src3, tgt3, E3, 0.5f,  125, slots3);
    concatWT_kernel<<<(64 * 128 + 255) / 256, 256, 0, stream>>>(W1, R1, 64, 128, KC, 1, WfT1);
    concatWTperm_kernel<<<(64 * KPAD + 255) / 256, 256, 0, stream>>>(W2, R2, 64, WfT2);
    concatWTperm_kernel<<<(128 * KPAD + 255) / 256, 256, 0, stream>>>(W3, R3, 128, WfT3);

    // --- pool prep ---
    zero_kernel<<<(16 * 128 + 16 + 255) / 256, 256, 0, stream>>>(gnum, 16 * 128 + 16);
    cid_kernel<<<(n3 + 255) / 256, 256, 0, stream>>>(batch, idx1, idx2, n3, cid, cnt);

    // --- level 1: MFMA histogram + GEMM(K=128) ---
    histo1_kernel<<<n1 / 4, 256, 0, stream>>>(slots1, rp1, A1buf);
    {
        dim3 g1(n1 / 64, 1, 1);
        gemm_kernel<<<g1, 256, 0, stream>>>(A1buf, WfT1, n1, 64, 128, 128, P);
        combine_kernel<<<(n1 * 64 + 255) / 256, 256, 0, stream>>>(P, b1, n1, 64, 1, x1);
    }
    xgather_kernel<<<(n2 * 64 + 255) / 256, 256, 0, stream>>>(x1, idx1, n2, x2in);

    // --- level 2 ---
    run_level(slots2, src2, rp2, x2in, WfT2, b2, n2, 64, Abuf, rows2, P, x2o, stream);
    xgather_kernel<<<(n3 * 64 + 255) / 256, 256, 0, stream>>>(x2o, idx2, n3, x3in);

    // --- level 3 ---
    run_level(slots3, src3, rp3, x3in, WfT3, b3, n3, 128, Abuf, rows3, P, x3o, stream);

    // --- pool + head ---
    pool2_kernel<<<(n3 + 63) / 64, 256, 0, stream>>>(x3o, cid, n3, gnum);
    mlp_kernel<<<16, 256, 0, stream>>>(gnum, cnt, lw1, lb1, lw2, lb2, lw3, lb3, out);
}

// Round 16
// 406.651 us; speedup vs baseline: 1.1290x; 1.1290x over previous
//
#include <hip/hip_runtime.h>
#include <hip/hip_bf16.h>
#include <math.h>

#define KDIM 5
#define KC 125
#define KPAD 8192   // 125*64 spline rows + 64 root rows + 128 zero pad (levels 2/3)
#define EPB 32      // max_nb = 32 -> deg <= 32 always
#define NSPLIT 4    // GEMM K-split for levels 2/3
#define LDA 72      // GEMM LDS tile row stride in bf16 (64 + 8 pad)
#define SSTR 40     // buildA S row stride in bf16
#define XSTR 40     // buildA XT row stride in bf16
#define H1STR 40    // histo1 S row stride in bf16

typedef short bf16x8 __attribute__((ext_vector_type(8)));
typedef float f32x4 __attribute__((ext_vector_type(4)));

__device__ __forceinline__ float elu_f(float x) { return x > 0.f ? x : (expf(x) - 1.f); }

__device__ __forceinline__ void fadd_atomic(float* p, float v) {
    unsafeAtomicAdd(p, v);
}

__device__ __forceinline__ unsigned short f2bf(float x) {
    union { float f; unsigned u; } v; v.f = x;
    unsigned r = (v.u + 0x7FFFu + ((v.u >> 16) & 1u)) >> 16;
    return (unsigned short)r;
}
__device__ __forceinline__ unsigned pack2(float lo, float hi) {
    __hip_bfloat162 h = __float22bfloat162_rn(make_float2(lo, hi));
    unsigned r; __builtin_memcpy(&r, &h, 4); return r;
}

// ---------------- rowptr ----------------
__global__ void rowptr_kernel(const int* __restrict__ tgt, int E, int n, int* __restrict__ rowptr)
{
    int e = blockIdx.x * blockDim.x + threadIdx.x;
    if (e > E) return;
    if (e < E) {
        int t = tgt[e];
        int p = (e == 0) ? -1 : tgt[e - 1];
        for (int v = p + 1; v <= t; v++) rowptr[v] = e;
    } else {
        int p = tgt[E - 1];
        for (int v = p + 1; v <= n; v++) rowptr[v] = E;
    }
}

// ---------------- slot table ----------------
__global__ void slots_kernel(const float* __restrict__ posL, const int* __restrict__ src,
                             const int* __restrict__ tgt, int E, float rinv2, int sinkrow,
                             unsigned* __restrict__ slots)
{
    int e = blockIdx.x * blockDim.x + threadIdx.x;
    if (e >= E) return;
    int s = src[e], t = tgt[e];
    float p0 = fminf(fmaxf((posL[t*3+0] - posL[s*3+0]) * rinv2 + 0.5f, 0.f), 1.f);
    float p1 = fminf(fmaxf((posL[t*3+1] - posL[s*3+1]) * rinv2 + 0.5f, 0.f), 1.f);
    float p2 = fminf(fmaxf((posL[t*3+2] - posL[s*3+2]) * rinv2 + 0.5f, 0.f), 1.f);
    float v0 = p0 * (KDIM - 1), v1 = p1 * (KDIM - 1), v2 = p2 * (KDIM - 1);
    int b0 = (int)floorf(v0), b1 = (int)floorf(v1), b2 = (int)floorf(v2);
    float f0 = v0 - (float)b0, f1 = v1 - (float)b1, f2 = v2 - (float)b2;
    unsigned out[8];
    #pragma unroll
    for (int sb = 0; sb < 8; sb++) {
        int i0 = sb & 1, i1 = (sb >> 1) & 1, i2 = (sb >> 2) & 1;
        float w = (i0 ? f0 : 1.f - f0) * (i1 ? f1 : 1.f - f1) * (i2 ? f2 : 1.f - f2);
        int k0 = min(b0 + i0, KDIM - 1), k1 = min(b1 + i1, KDIM - 1), k2 = min(b2 + i2, KDIM - 1);
        int wi = k0 + KDIM * k1 + KDIM * KDIM * k2;
        if (w == 0.f) wi = sinkrow;
        out[sb] = (__float_as_uint(w) & ~127u) | (unsigned)wi;
    }
    uint4* dst = (uint4*)&slots[(size_t)e * 8];
    dst[0] = make_uint4(out[0], out[1], out[2], out[3]);
    dst[1] = make_uint4(out[4], out[5], out[6], out[7]);
}

// ---------------- Level 1 histogram via MFMA row-sum (atomic-free) ----------------
__global__ __launch_bounds__(256) void histo1_kernel(const unsigned* __restrict__ slots,
                                                     const int* __restrict__ rowptr,
                                                     unsigned short* __restrict__ Aout)
{
    __shared__ __attribute__((aligned(16))) unsigned short S[4][128 * H1STR];
    int wave = threadIdx.x >> 6, lane = threadIdx.x & 63;
    int node = blockIdx.x * 4 + wave;
    int rs = rowptr[node], re = rowptr[node + 1];
    int deg = re - rs;
    unsigned short* Sw = S[wave];

    for (int i = lane; i < 128 * H1STR / 8; i += 64)
        ((uint4*)Sw)[i] = make_uint4(0, 0, 0, 0);

    int wbase = lane * 4;
    if (wbase < deg * 8) {
        uint4 sw = *(const uint4*)&slots[(size_t)rs * 8 + wbase];
        unsigned wd[4] = {sw.x, sw.y, sw.z, sw.w};
        #pragma unroll
        for (int j = 0; j < 4; j++) {
            int e = (wbase + j) >> 3;
            int wi = wd[j] & 127u;
            Sw[wi * H1STR + e] = f2bf(__uint_as_float(wd[j] & ~127u));
        }
    }
    __syncthreads();

    const short one = 0x3F80;
    bf16x8 bones = {one, one, one, one, one, one, one, one};
    int fr = lane & 15, fq = (lane >> 4) * 8;
    f32x4 acc[8];
    #pragma unroll
    for (int tl = 0; tl < 8; tl++) {
        bf16x8 af = *(const bf16x8*)&Sw[(tl * 16 + fr) * H1STR + fq];
        acc[tl] = __builtin_amdgcn_mfma_f32_16x16x32_bf16(
            af, bones, (f32x4){0.f, 0.f, 0.f, 0.f}, 0, 0, 0);
    }

    float invdeg = 1.f / fmaxf((float)deg, 1.f);
    if ((lane & 15) == 0) {
        int rbase = (lane >> 4) * 4;
        #pragma unroll
        for (int tl = 0; tl < 8; tl++)
            #pragma unroll
            for (int r = 0; r < 4; r++) {
                int row = tl * 16 + rbase + r;
                float v = (row < KC) ? acc[tl][r] * invdeg : (row == KC ? 1.f : 0.f);
                Sw[row] = f2bf(v);
            }
    }
    __syncthreads();
    unsigned lo = Sw[2 * lane], hi = Sw[2 * lane + 1];
    ((unsigned*)(Aout + (size_t)node * 128))[lane] = lo | (hi << 16);
}

// ---------------- buildA (levels 2/3): MFMA, direct writeout (round-13 epilogue) ----------
__global__ __launch_bounds__(256) void buildA_kernel(
    const unsigned* __restrict__ slots, const int* __restrict__ src,
    const int* __restrict__ rowptr, const unsigned short* __restrict__ xbf,
    int nodeBase, unsigned short* __restrict__ Aout)
{
    __shared__ __attribute__((aligned(16))) unsigned short S[128 * SSTR];   // S[wi][e]
    __shared__ __attribute__((aligned(16))) unsigned short XT[64 * XSTR];   // XT[c][e]
    __shared__ int Es[EPB];
    int node = nodeBase + blockIdx.x;
    int t = threadIdx.x;                      // blockDim = 256
    int rs = rowptr[node], re = rowptr[node + 1];
    int ne = re - rs;                         // <= 32 (max_nb)
    int wave = t >> 6, lane = t & 63;
    int fr = lane & 15, fq = (lane >> 4) * 8;

    for (int i = t; i < 128 * SSTR / 2; i += 256) ((unsigned*)S)[i] = 0;
    for (int i = t; i < 64 * XSTR / 2; i += 256) ((unsigned*)XT)[i] = 0;
    if (t < ne) Es[t] = src[rs + t];
    __syncthreads();
    if (t < ne * 8) {
        int e = t >> 3;
        unsigned word = slots[(size_t)rs * 8 + t];
        int wi = word & 127u;
        S[wi * SSTR + e] = f2bf(__uint_as_float(word & ~127u));
    }
    for (int i = t; i < ne * 64; i += 256) {
        int c = i & 63, el = i >> 6;
        XT[c * XSTR + el] = xbf[(size_t)Es[el] * 64 + c];
    }
    __syncthreads();

    f32x4 acc[2][4];
    #pragma unroll
    for (int i = 0; i < 2; i++)
        #pragma unroll
        for (int j = 0; j < 4; j++) acc[i][j] = (f32x4){0.f, 0.f, 0.f, 0.f};
    #pragma unroll
    for (int i = 0; i < 2; i++) {
        bf16x8 af = *(const bf16x8*)&S[((2 * wave + i) * 16 + fr) * SSTR + fq];
        #pragma unroll
        for (int j = 0; j < 4; j++) {
            bf16x8 bg = *(const bf16x8*)&XT[(j * 16 + fr) * XSTR + fq];
            acc[i][j] = __builtin_amdgcn_mfma_f32_16x16x32_bf16(af, bg, acc[i][j], 0, 0, 0);
        }
    }

    float invdeg = 1.f / fmaxf((float)ne, 1.f);
    unsigned short* out = Aout + (size_t)blockIdx.x * KPAD;
    int quad = lane >> 4;
    #pragma unroll
    for (int i = 0; i < 2; i++) {
        int wibase = (2 * wave + i) * 16 + quad * 4;
        #pragma unroll
        for (int r = 0; r < 4; r++) {
            int wi = wibase + r;
            if (wi < KC) {
                #pragma unroll
                for (int j = 0; j < 4; j++)
                    out[wi * 64 + j * 16 + fr] = f2bf(acc[i][j][r] * invdeg);
            }
        }
    }
    if (t < 64) out[8000 + t] = xbf[(size_t)node * 64 + t];
    if (t < 128) out[8064 + t] = 0;
}

// ---------------- concat + transpose weights to bf16: WfT[n][k], K padded ----------------
__global__ void concatWT_kernel(const float* __restrict__ W, const float* __restrict__ R,
                                int COUT, int kpad, int krows, int cin,
                                unsigned short* __restrict__ WfT)
{
    int i = blockIdx.x * blockDim.x + threadIdx.x;
    if (i >= COUT * kpad) return;
    int n = i / kpad, k = i - n * kpad;
    float v = 0.f;
    if (k < krows) v = W[(size_t)k * COUT + n];
    else if (k < krows + cin) v = R[(size_t)(k - krows) * COUT + n];
    WfT[i] = f2bf(v);
}

// ---------------- bf16 MFMA GEMM, double-buffered LDS ----------------
__global__ __launch_bounds__(256) void gemm_kernel(const unsigned short* __restrict__ A,
                                                   const unsigned short* __restrict__ BT,
                                                   int Mrows, int COUT, int Ksz, int lda,
                                                   float* __restrict__ P)
{
    __shared__ __attribute__((aligned(16))) unsigned short As[2 * 64 * LDA];
    __shared__ __attribute__((aligned(16))) unsigned short Bs[2 * 64 * LDA];
    int t = threadIdx.x;
    int mblk = blockIdx.x * 64, nblk = blockIdx.y * 64;
    int kBase = blockIdx.z * Ksz;

    int lr = t >> 2;
    int lc = (t & 3) * 16;

    const unsigned short* Ap = A + (size_t)(mblk + lr) * lda + kBase + lc;
    const unsigned short* Bp = BT + (size_t)(nblk + lr) * lda + kBase + lc;

    uint4 a0 = *(const uint4*)Ap;  uint4 a1 = *(const uint4*)(Ap + 8);
    uint4 b0 = *(const uint4*)Bp;  uint4 b1 = *(const uint4*)(Bp + 8);

    int wave = t >> 6, lane = t & 63;
    int mw = (wave & 1) * 32, nw = (wave >> 1) * 32;
    int fr = lane & 15;
    int fq = (lane >> 4) * 8;

    f32x4 acc[2][2];
    #pragma unroll
    for (int i = 0; i < 2; i++)
        #pragma unroll
        for (int j = 0; j < 2; j++) acc[i][j] = (f32x4){0.f, 0.f, 0.f, 0.f};

    *(uint4*)&As[lr * LDA + lc]     = a0;
    *(uint4*)&As[lr * LDA + lc + 8] = a1;
    *(uint4*)&Bs[lr * LDA + lc]     = b0;
    *(uint4*)&Bs[lr * LDA + lc + 8] = b1;
    __syncthreads();

    int ktiles = Ksz / 64;
    for (int kt = 0; kt < ktiles; kt++) {
        int cur = (kt & 1) * 64 * LDA;
        if (kt + 1 < ktiles) {
            Ap += 64; Bp += 64;
            a0 = *(const uint4*)Ap; a1 = *(const uint4*)(Ap + 8);
            b0 = *(const uint4*)Bp; b1 = *(const uint4*)(Bp + 8);
        }
        #pragma unroll
        for (int ks = 0; ks < 2; ks++) {
            bf16x8 af0 = *(const bf16x8*)&As[cur + (mw + fr) * LDA + ks * 32 + fq];
            bf16x8 af1 = *(const bf16x8*)&As[cur + (mw + 16 + fr) * LDA + ks * 32 + fq];
            bf16x8 bg0 = *(const bf16x8*)&Bs[cur + (nw + fr) * LDA + ks * 32 + fq];
            bf16x8 bg1 = *(const bf16x8*)&Bs[cur + (nw + 16 + fr) * LDA + ks * 32 + fq];
            acc[0][0] = __builtin_amdgcn_mfma_f32_16x16x32_bf16(af0, bg0, acc[0][0], 0, 0, 0);
            acc[0][1] = __builtin_amdgcn_mfma_f32_16x16x32_bf16(af0, bg1, acc[0][1], 0, 0, 0);
            acc[1][0] = __builtin_amdgcn_mfma_f32_16x16x32_bf16(af1, bg0, acc[1][0], 0, 0, 0);
            acc[1][1] = __builtin_amdgcn_mfma_f32_16x16x32_bf16(af1, bg1, acc[1][1], 0, 0, 0);
        }
        if (kt + 1 < ktiles) {
            int nxt = ((kt + 1) & 1) * 64 * LDA;
            *(uint4*)&As[nxt + lr * LDA + lc]     = a0;
            *(uint4*)&As[nxt + lr * LDA + lc + 8] = a1;
            *(uint4*)&Bs[nxt + lr * LDA + lc]     = b0;
            *(uint4*)&Bs[nxt + lr * LDA + lc + 8] = b1;
        }
        __syncthreads();
    }
    float* Pz = P + (size_t)blockIdx.z * Mrows * COUT;
    int crow = (lane >> 4) * 4, ccol = lane & 15;
    #pragma unroll
    for (int i = 0; i < 2; i++)
        #pragma unroll
        for (int j = 0; j < 2; j++) {
            int m0 = mblk + mw + i * 16 + crow;
            int n0 = nblk + nw + j * 16 + ccol;
            #pragma unroll
            for (int r = 0; r < 4; r++)
                Pz[(size_t)(m0 + r) * COUT + n0] = acc[i][j][r];
        }
}

// ---------------- combine K-split partials + bias + ELU ----------------
__global__ void combine_kernel(const float* __restrict__ P, const float* __restrict__ b,
                               int Mrows, int COUT, int NS, float* __restrict__ xout)
{
    int i = blockIdx.x * blockDim.x + threadIdx.x;
    int total = Mrows * COUT;
    if (i >= total) return;
    float s = 0.f;
    for (int z = 0; z < NS; z++) s += P[(size_t)z * total + i];
    int o = i % COUT;
    xout[i] = elu_f(s + b[o]);
}

// ---------------- gathers ----------------
__global__ void xgather_kernel(const float* __restrict__ x_src, const int* __restrict__ idx,
                               int n, unsigned short* __restrict__ x_dst)
{
    int tid = blockIdx.x * blockDim.x + threadIdx.x;
    if (tid >= n * 64) return;
    int i = tid >> 6, c = tid & 63;
    x_dst[tid] = f2bf(x_src[(size_t)idx[i] * 64 + c]);
}

__global__ void posgather_kernel(const float* __restrict__ pos_src, const int* __restrict__ idx,
                                 int n, float* __restrict__ pos_dst)
{
    int tid = blockIdx.x * blockDim.x + threadIdx.x;
    if (tid >= n * 3) return;
    int i = tid / 3, d = tid - i * 3;
    pos_dst[tid] = pos_src[idx[i] * 3 + d];
}

__global__ void zero_kernel(float* __restrict__ p, int n)
{
    int i = blockIdx.x * blockDim.x + threadIdx.x;
    if (i < n) p[i] = 0.f;
}

// ---------------- cloud ids + counts ----------------
__global__ void cid_kernel(const int* __restrict__ batch, const int* __restrict__ idx1,
                           const int* __restrict__ idx2, int n3,
                           int* __restrict__ cid, float* __restrict__ cnt)
{
    __shared__ int h[16];
    int t = threadIdx.x;
    int i = blockIdx.x * 256 + t;
    if (t < 16) h[t] = 0;
    __syncthreads();
    if (i < n3) {
        int cl = batch[idx1[idx2[i]]];
        cid[i] = cl;
        atomicAdd(&h[cl], 1);
    }
    __syncthreads();
    if (t < 16 && h[t] > 0) fadd_atomic(&cnt[t], (float)h[t]);
}

// ---------------- Mean-pool stage ----------------
__global__ void pool2_kernel(const float* __restrict__ x3, const int* __restrict__ cid,
                             int n3, float* __restrict__ gnum)
{
    int t = threadIdx.x;
    int c = t & 127, h = t >> 7;
    int base = blockIdx.x * 64;
    int nn = min(64, n3 - base);
    float sum = 0.f; int cur = -1;
    for (int j = h; j < nn; j += 2) {
        int i = base + j;
        int cl = cid[i];
        if (cl != cur) {
            if (cur >= 0) fadd_atomic(&gnum[cur * 128 + c], sum);
            cur = cl; sum = 0.f;
        }
        sum += x3[(size_t)i * 128 + c];
    }
    if (cur >= 0) fadd_atomic(&gnum[cur * 128 + c], sum);
}

// ---------------- Final MLP + log_softmax ----------------
__global__ void mlp_kernel(const float* __restrict__ gnum, const float* __restrict__ cnt,
                           const float* __restrict__ lw1, const float* __restrict__ lb1,
                           const float* __restrict__ lw2, const float* __restrict__ lb2,
                           const float* __restrict__ lw3, const float* __restrict__ lb3,
                           float* __restrict__ out)
{
    __shared__ float gv[128], h1[256], h2[256], lg[10];
    __shared__ float lse_s;
    int cl = blockIdx.x, t = threadIdx.x;   // blockDim = 256
    if (t < 128) gv[t] = gnum[cl * 128 + t] / fmaxf(cnt[cl], 1.f);
    __syncthreads();
    float a = lb1[t];
    for (int c = 0; c < 128; c++) a += gv[c] * lw1[c * 256 + t];
    h1[t] = elu_f(a);
    __syncthreads();
    a = lb2[t];
    for (int c = 0; c < 256; c++) a += h1[c] * lw2[c * 256 + t];
    h2[t] = elu_f(a);
    __syncthreads();
    if (t < 10) {
        a = lb3[t];
        for (int c = 0; c < 256; c++) a += h2[c] * lw3[c * 10 + t];
        lg[t] = a;
    }
    __syncthreads();
    if (t == 0) {
        float m = -1e30f;
        for (int i = 0; i < 10; i++) m = fmaxf(m, lg[i]);
        float s = 0.f;
        for (int i = 0; i < 10; i++) s += expf(lg[i] - m);
        lse_s = m + logf(s);
    }
    __syncthreads();
    if (t < 10) out[cl * 10 + t] = lg[t] - lse_s;
}

static void run_level(const unsigned* slots, const int* src, const int* rowptr,
                      const unsigned short* xbf, const unsigned short* WfT, const float* bvec,
                      int n, int COUT, unsigned short* Abuf, int AbufRows, float* P,
                      float* xout, hipStream_t stream)
{
    int Ksz = KPAD / NSPLIT;
    for (int cs = 0; cs < n; cs += AbufRows) {
        int cr = min(AbufRows, n - cs);
        buildA_kernel<<<cr, 256, 0, stream>>>(slots, src, rowptr, xbf, cs, Abuf);
        dim3 grid(cr / 64, COUT / 64, NSPLIT);
        gemm_kernel<<<grid, 256, 0, stream>>>(Abuf, WfT, cr, COUT, Ksz, KPAD, P);
        combine_kernel<<<(cr * COUT + 255) / 256, 256, 0, stream>>>(P, bvec, cr, COUT, NSPLIT,
                                                                    xout + (size_t)cs * COUT);
    }
}

extern "C" void kernel_launch(void* const* d_in, const int* in_sizes, int n_in,
                              void* d_out, int out_size, void* d_ws, size_t ws_size,
                              hipStream_t stream)
{
    const float* pos   = (const float*)d_in[0];
    const int*   batch = (const int*)d_in[1];
    const int*   src1  = (const int*)d_in[2];
    const int*   tgt1  = (const int*)d_in[3];
    const int*   src2  = (const int*)d_in[4];
    const int*   tgt2  = (const int*)d_in[5];
    const int*   src3  = (const int*)d_in[6];
    const int*   tgt3  = (const int*)d_in[7];
    const int*   idx1  = (const int*)d_in[8];
    const int*   idx2  = (const int*)d_in[9];
    const float* W1 = (const float*)d_in[10];
    const float* R1 = (const float*)d_in[11];
    const float* b1 = (const float*)d_in[12];
    const float* W2 = (const float*)d_in[13];
    const float* R2 = (const float*)d_in[14];
    const float* b2 = (const float*)d_in[15];
    const float* W3 = (const float*)d_in[16];
    const float* R3 = (const float*)d_in[17];
    const float* b3 = (const float*)d_in[18];
    const float* lw1 = (const float*)d_in[19];
    const float* lb1 = (const float*)d_in[20];
    const float* lw2 = (const float*)d_in[21];
    const float* lb2 = (const float*)d_in[22];
    const float* lw3 = (const float*)d_in[23];
    const float* lb3 = (const float*)d_in[24];

    int n1 = in_sizes[0] / 3;
    int E1 = in_sizes[2];
    int E2 = in_sizes[4];
    int E3 = in_sizes[6];
    int n2 = in_sizes[8];
    int n3 = in_sizes[9];

    float* ws = (float*)d_ws;
    float* x1   = ws;                               // n1*64 f32
    float* x2o  = x1   + (size_t)n1 * 64;           // n2*64 f32
    float* x3o  = x2o  + (size_t)n2 * 64;           // n3*128 f32
    float* pos2 = x3o  + (size_t)n3 * 128;          // n2*3
    float* pos3 = pos2 + (size_t)n2 * 3;            // n3*3
    float* gnum = pos3 + (size_t)n3 * 3;            // 16*128
    float* cnt  = gnum + 16 * 128;                  // 16
    int*   cid  = (int*)(cnt + 16);                 // n3
    unsigned short* x2in = (unsigned short*)(cid + ((n3 + 4) & ~3));   // n2*64 bf16
    unsigned short* x3in = x2in + (size_t)n2 * 64;                     // n3*64 bf16
    unsigned short* WfT1 = x3in + (size_t)n3 * 64;                     // 64*128 bf16
    unsigned short* WfT2 = WfT1 + (size_t)64 * 128;        // 64*KPAD
    unsigned short* WfT3 = WfT2 + (size_t)64 * KPAD;       // 128*KPAD
    int*   rp1  = (int*)(WfT3 + (size_t)128 * KPAD);
    int*   rp2  = rp1 + ((n1 + 4) & ~3);
    int*   rp3  = rp2 + ((n2 + 4) & ~3);
    unsigned* slots1 = (unsigned*)(rp3 + ((n3 + 4) & ~3));
    unsigned* slots2 = slots1 + (size_t)E1 * 8;
    unsigned* slots3 = slots2 + (size_t)E2 * 8;
    unsigned short* A1buf = (unsigned short*)(slots3 + (size_t)E3 * 8);  // n1*128 bf16
    float*  P    = (float*)(A1buf + (size_t)n1 * 128);  // 8M floats
    unsigned short* Abuf = (unsigned short*)(P + (size_t)8 * 1024 * 1024);

    size_t usedBytes = (size_t)((char*)Abuf - (char*)ws);
    size_t availBytes = ws_size > usedBytes ? ws_size - usedBytes : 0;
    int maxRows = (int)(availBytes / ((size_t)KPAD * 2));
    maxRows &= ~63;
    if (maxRows < 64) maxRows = 64;
    int rowsP2 = ((8 * 1024 * 1024) / (NSPLIT * 64)) & ~63;
    int rowsP3 = ((8 * 1024 * 1024) / (NSPLIT * 128)) & ~63;
    int rows2 = min(min(maxRows, rowsP2), n2);
    int rows3 = min(min(maxRows, rowsP3), n3);

    float* out = (float*)d_out;

    // --- graph preprocessing ---
    rowptr_kernel<<<(E1 + 256) / 256, 256, 0, stream>>>(tgt1, E1, n1, rp1);
    rowptr_kernel<<<(E2 + 256) / 256, 256, 0, stream>>>(tgt2, E2, n2, rp2);
    rowptr_kernel<<<(E3 + 256) / 256, 256, 0, stream>>>(tgt3, E3, n3, rp3);
    posgather_kernel<<<(n2 * 3 + 255) / 256, 256, 0, stream>>>(pos, idx1, n2, pos2);
    posgather_kernel<<<(n3 * 3 + 255) / 256, 256, 0, stream>>>(pos2, idx2, n3, pos3);
    slots_kernel<<<(E1 + 255) / 256, 256, 0, stream>>>(pos,  src1, tgt1, E1, 2.5f,  126, slots1);
    slots_kernel<<<(E2 + 255) / 256, 256, 0, stream>>>(pos2, src2, tgt2, E2, 1.25f, 125, slots2);
    slots_kernel<<<(E3 + 255) / 256, 256, 0, stream>>>(pos3, src3, tgt3, E3, 0.5f,  125, slots3);
    concatWT_kernel<<<(64 * 128 + 255) / 256, 256, 0, stream>>>(W1, R1, 64, 128, KC, 1, WfT1);
    concatWT_kernel<<<(64 * KPAD + 255) / 256, 256, 0, stream>>>(W2, R2, 64, KPAD, KC * 64, 64, WfT2);
    concatWT_kernel<<<(128 * KPAD + 255) / 256, 256, 0, stream>>>(W3, R3, 128, KPAD, KC * 64, 64, WfT3);

    // --- pool prep ---
    zero_kernel<<<(16 * 128 + 16 + 255) / 256, 256, 0, stream>>>(gnum, 16 * 128 + 16);
    cid_kernel<<<(n3 + 255) / 256, 256, 0, stream>>>(batch, idx1, idx2, n3, cid, cnt);

    // --- level 1: MFMA histogram + GEMM(K=128) ---
    histo1_kernel<<<n1 / 4, 256, 0, stream>>>(slots1, rp1, A1buf);
    {
        dim3 g1(n1 / 64, 1, 1);
        gemm_kernel<<<g1, 256, 0, stream>>>(A1buf, WfT1, n1, 64, 128, 128, P);
        combine_kernel<<<(n1 * 64 + 255) / 256, 256, 0, stream>>>(P, b1, n1, 64, 1, x1);
    }
    xgather_kernel<<<(n2 * 64 + 255) / 256, 256, 0, stream>>>(x1, idx1, n2, x2in);

    // --- level 2 ---
    run_level(slots2, src2, rp2, x2in, WfT2, b2, n2, 64, Abuf, rows2, P, x2o, stream);
    xgather_kernel<<<(n3 * 64 + 255) / 256, 256, 0, stream>>>(x2o, idx2, n3, x3in);

    // --- level 3 ---
    run_level(slots3, src3, rp3, x3in, WfT3, b3, n3, 128, Abuf, rows3, P, x3o, stream);

    // --- pool + head ---
    pool2_kernel<<<(n3 + 63) / 64, 256, 0, stream>>>(x3o, cid, n3, gnum);
    mlp_kernel<<<16, 256, 0, stream>>>(gnum, cnt, lw1, lb1, lw2, lb2, lw3, lb3, out);
}